// Round 14
// baseline (348.895 us; speedup 1.0000x reference)
//
#include <hip/hip_runtime.h>

#define NTOT 131072   // B*T
#define KCB  512
#define DIM  64

typedef __attribute__((ext_vector_type(8))) short bf16x8;
typedef __attribute__((ext_vector_type(4))) float f32x4;

__device__ __forceinline__ unsigned short f2bf(float f) {
  unsigned u = __float_as_uint(f);
  u = u + 0x7FFFu + ((u >> 16) & 1u);          // RNE
  return (unsigned short)(u >> 16);
}
__device__ __forceinline__ float bf2f(unsigned short h) {
  return __uint_as_float(((unsigned)h) << 16);
}
__device__ __forceinline__ float wave_sum(float v) {
#pragma unroll
  for (int off = 32; off; off >>= 1) v += __shfl_xor(v, off, 64);
  return v;
}

// ---------------------------------------------------------------------------
// K0: embsq = |e_k|^2 ; e' = -2e split into bf16 hi/lo tables [K][D]
// ---------------------------------------------------------------------------
__global__ __launch_bounds__(512, 1) void k_prep(
    const float* __restrict__ emb, unsigned short* __restrict__ eh,
    unsigned short* __restrict__ el, float* __restrict__ embsq)
{
  const int k = threadIdx.x;
  float sq = 0.f;
#pragma unroll 8
  for (int d = 0; d < DIM; ++d) {
    const float e = emb[k * DIM + d];
    sq = fmaf(e, e, sq);
    const float m = -2.f * e;
    const unsigned short h = f2bf(m);
    eh[k * DIM + d] = h;
    el[k * DIM + d] = f2bf(m - bf2f(h));
  }
  embsq[k] = sq;
}

// ---------------------------------------------------------------------------
// K1 (round 14): MFMA split-bf16 distance GEMM, LOW REGISTER PRESSURE.
// Identical math to round 13 (verified correct), but the accumulator lives
// only per-(kg,rg): one f32x4 computed by 6 MFMAs then immediately retired
// through its 4-element epilogue. Live set ~170 VGPR (R13 kept acc[4][4] +
// mn + af live through the chunk epilogue => ~220+ => spill => 320us).
// LDS: 128K xls + 2K xsq + 2K kmin = 132 KiB -> 1 block/CU.
// ---------------------------------------------------------------------------
__global__ __launch_bounds__(512, 2) void k_dist(
    const float* __restrict__ x_g,              // [D][N]
    const unsigned short* __restrict__ eh_g,    // [K][D] bf16 hi of -2e
    const unsigned short* __restrict__ el_g,    // [K][D] bf16 lo
    const float* __restrict__ embsq,            // [K]
    float* __restrict__ dist_out,               // [N][K]
    float* __restrict__ enc_out,                // [N][K]
    int* __restrict__ idx_out,                  // [N]
    unsigned* __restrict__ cnt_g,               // [K]
    float* __restrict__ dw_g)                   // [K][D]
{
  __shared__ unsigned short xls[8][2][64][64];  // [wave][hi/lo][row][d] swizzled
  __shared__ float xsq_l[8][64];
  __shared__ int   kmin_l[8][64];

  const int t = threadIdx.x;
  const int lane = t & 63;
  const int w = t >> 6;
  const int n0 = blockIdx.x * 512 + w * 64;     // wave's 64 rows

  // ---- stage: lane owns row n0+lane (coalesced over n per d)
  {
    float sq = 0.f;
#pragma unroll
    for (int half = 0; half < 2; ++half) {
      float v[32];
#pragma unroll
      for (int d = 0; d < 32; ++d)
        v[d] = x_g[(size_t)(half * 32 + d) * NTOT + n0 + lane];
#pragma unroll
      for (int d = 0; d < 32; ++d) {
        const float f = v[d];
        sq = fmaf(f, f, sq);
        const unsigned short h = f2bf(f);
        const unsigned short lo = f2bf(f - bf2f(h));
        const int dd = half * 32 + d;
        // 16B-chunk XOR swizzle: chunk' = (dd>>3) ^ (row&7)
        const int pos = ((((dd >> 3) ^ (lane & 7)) << 3) | (dd & 7));
        xls[w][0][lane][pos] = h;
        xls[w][1][lane][pos] = lo;
      }
    }
    xsq_l[w][lane] = sq;
  }
  asm volatile("" ::: "memory");   // wave-sync: staging before frag reads

  // ---- A-frags (x) held for whole kernel: [rowgroup][d-step][hi/lo]
  bf16x8 af[4][2][2];
#pragma unroll
  for (int rg = 0; rg < 4; ++rg) {
    const int row = rg * 16 + (lane & 15);
#pragma unroll
    for (int ds = 0; ds < 2; ++ds) {
      const int c = (ds * 4 + (lane >> 4)) ^ (row & 7);
#pragma unroll
      for (int hl = 0; hl < 2; ++hl)
        af[rg][ds][hl] =
            *reinterpret_cast<const bf16x8*>(&xls[w][hl][row][c << 3]);
    }
  }

  // ---- |x|^2 for this lane's 16 output rows (C layout: row=(l>>4)*4+j)
  float xsq_r[4][4];
#pragma unroll
  for (int rg = 0; rg < 4; ++rg)
#pragma unroll
    for (int j = 0; j < 4; ++j)
      xsq_r[rg][j] = xsq_l[w][rg * 16 + (lane >> 4) * 4 + j];

  unsigned long long mn[4][4];
#pragma unroll
  for (int rg = 0; rg < 4; ++rg)
#pragma unroll
    for (int j = 0; j < 4; ++j) mn[rg][j] = ~0ull;

  // ---- main loop over 8 k-chunks of 64 codes; acc retired per (kg,rg)
  for (int kc = 0; kc < 8; ++kc) {
    const int kbase = kc * 64;
#pragma unroll
    for (int kg = 0; kg < 4; ++kg) {
      const int kcode = kbase + kg * 16 + (lane & 15);
      const unsigned short* ph = eh_g + kcode * 64 + (lane >> 4) * 8;
      const unsigned short* pl = el_g + kcode * 64 + (lane >> 4) * 8;
      const bf16x8 beh0 = *reinterpret_cast<const bf16x8*>(ph);
      const bf16x8 beh1 = *reinterpret_cast<const bf16x8*>(ph + 32);
      const bf16x8 bel0 = *reinterpret_cast<const bf16x8*>(pl);
      const bf16x8 bel1 = *reinterpret_cast<const bf16x8*>(pl + 32);
      const unsigned kk0 = (unsigned)kcode;
      const float eq = embsq[kk0];
#pragma unroll
      for (int rg = 0; rg < 4; ++rg) {
        f32x4 a = (f32x4){0.f, 0.f, 0.f, 0.f};
        a = __builtin_amdgcn_mfma_f32_16x16x32_bf16(af[rg][0][0], beh0, a, 0, 0, 0);
        a = __builtin_amdgcn_mfma_f32_16x16x32_bf16(af[rg][0][0], bel0, a, 0, 0, 0);
        a = __builtin_amdgcn_mfma_f32_16x16x32_bf16(af[rg][0][1], beh0, a, 0, 0, 0);
        a = __builtin_amdgcn_mfma_f32_16x16x32_bf16(af[rg][1][0], beh1, a, 0, 0, 0);
        a = __builtin_amdgcn_mfma_f32_16x16x32_bf16(af[rg][1][0], bel1, a, 0, 0, 0);
        a = __builtin_amdgcn_mfma_f32_16x16x32_bf16(af[rg][1][1], beh1, a, 0, 0, 0);
        // immediate epilogue: dist = a + |x|^2 + |e|^2, store + running min
#pragma unroll
        for (int j = 0; j < 4; ++j) {
          const float dist = a[j] + xsq_r[rg][j] + eq;
          dist_out[(size_t)(n0 + rg * 16 + (lane >> 4) * 4 + j) * KCB + kk0] = dist;
          const unsigned long long pk =
              ((unsigned long long)__float_as_uint(dist) << 32) | kk0;
          mn[rg][j] = pk < mn[rg][j] ? pk : mn[rg][j];
        }
      }
    }
  }

  // ---- reduce argmin across the 16 lanes sharing (lane>>4)
#pragma unroll
  for (int rg = 0; rg < 4; ++rg)
#pragma unroll
    for (int j = 0; j < 4; ++j) {
#pragma unroll
      for (int m = 1; m < 16; m <<= 1) {
        const unsigned long long o = __shfl_xor(mn[rg][j], m, 64);
        mn[rg][j] = o < mn[rg][j] ? o : mn[rg][j];
      }
    }
  if ((lane & 15) == 0) {
#pragma unroll
    for (int rg = 0; rg < 4; ++rg)
#pragma unroll
      for (int j = 0; j < 4; ++j)
        kmin_l[w][rg * 16 + (lane >> 4) * 4 + j] =
            (int)(mn[rg][j] & 0xFFFFFFFFull);
  }
  asm volatile("" ::: "memory");   // wave-sync: kmin visible to all lanes

  // ---- idx + cnt (lane owns row n0+lane)
  {
    const int km = kmin_l[w][lane];
    idx_out[n0 + lane] = km;
    atomicAdd(&cnt_g[km], 1u);
  }

  // ---- enc one-hot rows + dw scatter
  for (int r = 0; r < 64; ++r) {
    const int km = kmin_l[w][r];          // uniform (broadcast read)
    const int base = lane * 8;
    float4 z0, z1;
    z0.x = (km == base)     ? 1.f : 0.f;
    z0.y = (km == base + 1) ? 1.f : 0.f;
    z0.z = (km == base + 2) ? 1.f : 0.f;
    z0.w = (km == base + 3) ? 1.f : 0.f;
    z1.x = (km == base + 4) ? 1.f : 0.f;
    z1.y = (km == base + 5) ? 1.f : 0.f;
    z1.z = (km == base + 6) ? 1.f : 0.f;
    z1.w = (km == base + 7) ? 1.f : 0.f;
    float* ep = enc_out + (size_t)(n0 + r) * KCB + base;
    *reinterpret_cast<float4*>(ep) = z0;
    *reinterpret_cast<float4*>(ep + 4) = z1;

    // dw[km][d=lane] += x'(row r, d=lane)   (x' = hi+lo, same value MFMA saw)
    const int pos = ((((lane >> 3) ^ (r & 7)) << 3) | (lane & 7));
    const float xv = bf2f(xls[w][0][r][pos]) + bf2f(xls[w][1][r][pos]);
    unsafeAtomicAdd(dw_g + ((size_t)km << 6) + lane, xv);
  }
}

// ---------------------------------------------------------------------------
// K3: cluster EMA + laplace + new_emb + perplexity (1 block, 512 threads)
// ---------------------------------------------------------------------------
__global__ __launch_bounds__(512, 1) void k_final(
    const float* __restrict__ ema_w, const float* __restrict__ ema_cs,
    const unsigned* __restrict__ cnt, const float* __restrict__ dw,
    float* __restrict__ nemb, float* __restrict__ out)
{
  __shared__ float red[8];
  __shared__ float bc;
  const int t = threadIdx.x;
  const int lane = t & 63, w = t >> 6;

  const float c = (float)cnt[t];
  const float craw = ema_cs[t] * 0.99f + 0.01f * c;

  float s = wave_sum(craw);
  if (lane == 0) red[w] = s;
  __syncthreads();
  if (t == 0) {
    float a = 0.f;
#pragma unroll
    for (int i = 0; i < 8; ++i) a += red[i];
    bc = a;
  }
  __syncthreads();
  const float n = bc;
  const float clus = (craw + 1e-5f) / (n + 512.f * 1e-5f) * n;

  const float4* wr = reinterpret_cast<const float4*>(ema_w + t * 64);
  const float4* dr = reinterpret_cast<const float4*>(dw + t * 64);
  float4* nr = reinterpret_cast<float4*>(nemb + t * 64);
#pragma unroll
  for (int q = 0; q < 16; ++q) {
    const float4 wv = wr[q], dv = dr[q];
    float4 o;
    o.x = (wv.x * 0.99f + 0.01f * dv.x) / clus;
    o.y = (wv.y * 0.99f + 0.01f * dv.y) / clus;
    o.z = (wv.z * 0.99f + 0.01f * dv.z) / clus;
    o.w = (wv.w * 0.99f + 0.01f * dv.w) / clus;
    nr[q] = o;
  }

  const float p = c * (1.f / 131072.f);
  const float term = p * logf(p + 1e-10f);
  float s2 = wave_sum(term);
  if (lane == 0) red[w] = s2;
  __syncthreads();
  if (t == 0) {
    float a = 0.f;
#pragma unroll
    for (int i = 0; i < 8; ++i) a += red[i];
    out[8388609] = expf(-a);   // perplexity slot
  }
}

// ---------------------------------------------------------------------------
// K4: quantized gather + transposed write + commitment loss
// ---------------------------------------------------------------------------
__global__ __launch_bounds__(256, 4) void k_quant(
    const float* __restrict__ x_g, const int* __restrict__ idx_g,
    const float* __restrict__ nemb, float* __restrict__ out)
{
  float lsum = 0.f;
  const int stride = gridDim.x * 256;
  for (int i = blockIdx.x * 256 + threadIdx.x; i < (DIM * NTOT / 4); i += stride) {
    const int d = i >> 15;                 // / (NTOT/4)
    const int n4 = i & ((NTOT / 4) - 1);
    const float4 xv = *reinterpret_cast<const float4*>(x_g + ((size_t)d << 17) + 4 * n4);
    const int4 id = *reinterpret_cast<const int4*>(idx_g + 4 * n4);
    const float q0 = nemb[(id.x << 6) + d];
    const float q1 = nemb[(id.y << 6) + d];
    const float q2 = nemb[(id.z << 6) + d];
    const float q3 = nemb[(id.w << 6) + d];
    const float e0 = q0 - xv.x, e1 = q1 - xv.y, e2 = q2 - xv.z, e3 = q3 - xv.w;
    float* op = out + 1 + ((size_t)d << 17) + 4 * n4;   // quantized_st region
    op[0] = xv.x + e0;
    op[1] = xv.y + e1;
    op[2] = xv.z + e2;
    op[3] = xv.w + e3;
    lsum += e0 * e0 + e1 * e1 + e2 * e2 + e3 * e3;
  }
  lsum = wave_sum(lsum);
  __shared__ float wsum[4];
  const int lane = threadIdx.x & 63, w = threadIdx.x >> 6;
  if (lane == 0) wsum[w] = lsum;
  __syncthreads();
  if (threadIdx.x == 0)
    unsafeAtomicAdd(out, (wsum[0] + wsum[1] + wsum[2] + wsum[3]) * (0.25f / 8388608.f));
}

// ---------------------------------------------------------------------------
extern "C" void kernel_launch(void* const* d_in, const int* in_sizes, int n_in,
                              void* d_out, int out_size, void* d_ws, size_t ws_size,
                              hipStream_t stream) {
  const float* x      = (const float*)d_in[0];   // [64][16][8192]
  const float* emb    = (const float*)d_in[1];   // [512][64]
  const float* ema_w  = (const float*)d_in[2];   // [512][64]
  const float* ema_cs = (const float*)d_in[3];   // [512]
  float* out = (float*)d_out;

  // d_out: loss@0 | q@1 (8388608) | perp@8388609 | enc@8388610 | dist@75497474
  float* enc_out  = out + 8388610;
  float* dist_out = out + 75497474;

  // ws: dw@0 (131072) | cnt@131072 (2048) | nemb@133120 (131072) |
  //     idx@264192 (524288) | embsq@788480 (2048) | eh@790528 (65536) |
  //     el@856064 (65536)
  char* ws = (char*)d_ws;
  float*          dw    = (float*)ws;
  unsigned*       cnt   = (unsigned*)(ws + 131072);
  float*          nemb  = (float*)(ws + 133120);
  int*            idx   = (int*)(ws + 264192);
  float*          embsq = (float*)(ws + 788480);
  unsigned short* eh    = (unsigned short*)(ws + 790528);
  unsigned short* el    = (unsigned short*)(ws + 856064);

  hipMemsetAsync(d_ws, 0, 133120, stream);          // zero dw + counts
  hipMemsetAsync(d_out, 0, sizeof(float), stream);  // zero loss accumulator

  k_prep<<<1, 512, 0, stream>>>(emb, eh, el, embsq);
  k_dist<<<256, 512, 0, stream>>>(x, eh, el, embsq, dist_out, enc_out, idx, cnt, dw);
  k_final<<<1, 512, 0, stream>>>(ema_w, ema_cs, cnt, dw, nemb, out);
  k_quant<<<2048, 256, 0, stream>>>(x, idx, nemb, out);
}

// Round 17
// 259.569 us; speedup vs baseline: 1.3441x; 1.3441x over previous
//
#include <hip/hip_runtime.h>

#define NTOT 131072   // B*T
#define KCB  512
#define DIM  64

typedef __attribute__((ext_vector_type(8))) short bf16x8;
typedef __attribute__((ext_vector_type(4))) float f32x4;

__device__ __forceinline__ unsigned short f2bf(float f) {
  unsigned u = __float_as_uint(f);
  u = u + 0x7FFFu + ((u >> 16) & 1u);          // RNE
  return (unsigned short)(u >> 16);
}
__device__ __forceinline__ float bf2f(unsigned short h) {
  return __uint_as_float(((unsigned)h) << 16);
}
__device__ __forceinline__ float wave_sum(float v) {
#pragma unroll
  for (int off = 32; off; off >>= 1) v += __shfl_xor(v, off, 64);
  return v;
}

// ---------------------------------------------------------------------------
// K0: embsq = |e_k|^2 ; e' = -2e split into bf16 hi/lo tables [K][D]
// ---------------------------------------------------------------------------
__global__ __launch_bounds__(512, 1) void k_prep(
    const float* __restrict__ emb, unsigned short* __restrict__ eh,
    unsigned short* __restrict__ el, float* __restrict__ embsq)
{
  const int k = threadIdx.x;
  float sq = 0.f;
#pragma unroll 8
  for (int d = 0; d < DIM; ++d) {
    const float e = emb[k * DIM + d];
    sq = fmaf(e, e, sq);
    const float m = -2.f * e;
    const unsigned short h = f2bf(m);
    eh[k * DIM + d] = h;
    el[k * DIM + d] = f2bf(m - bf2f(h));
  }
  embsq[k] = sq;
}

// ---------------------------------------------------------------------------
// K1 (round 17 = round 15 resubmit): MFMA GEMM, ZERO global loads in hot loop.
// R13/14 were slow because B-frag + embsq GLOBAL loads inside the kg loop
// forced a vmcnt store-drain every iteration (loads and stores share the
// in-order vmcnt counter). Now: e-tables in LDS (ds_read = lgkmcnt domain,
// independent of stores), embsq in 32 regs (kc fully unrolled -> static
// indexing), so dist stores stream freely like the R6 scalar kernel.
// 1024 blocks x 512 thr; wave owns 16 rows x all 512 codes.
// LDS: ehl 128K + xls 32K = 163840 B exactly (1 block/CU).
// ---------------------------------------------------------------------------
__global__ __launch_bounds__(512, 2) void k_dist(
    const float* __restrict__ x_g,              // [D][N]
    const unsigned short* __restrict__ eh_g,    // [K][D] bf16 hi of -2e
    const unsigned short* __restrict__ el_g,    // [K][D] bf16 lo
    const float* __restrict__ embsq,            // [K]
    float* __restrict__ dist_out,               // [N][K]
    float* __restrict__ enc_out,                // [N][K]
    int* __restrict__ idx_out,                  // [N]
    unsigned* __restrict__ cnt_g,               // [K]
    float* __restrict__ dw_g)                   // [K][D]
{
  __shared__ unsigned short ehl[2][KCB][DIM];   // [hi/lo][k][d] swizzled, 128K
  __shared__ unsigned short xls[8][2][16][DIM]; // [wave][hi/lo][row][d], 32K

  const int t = threadIdx.x;
  const int lane = t & 63;
  const int w = t >> 6;
  const int n0w = blockIdx.x * 128 + w * 16;    // wave's 16 rows
  const int lo = lane & 15;
  const int hi = lane >> 4;

  // ---- cooperative e-table staging: 16B-chunk swizzle chunk' = cl ^ (k&7)
#pragma unroll
  for (int i = 0; i < 8; ++i) {
    const int k = i * 64 + (t >> 3);
    const int cl = t & 7;
    const int pos = ((cl ^ (k & 7)) << 3);
    *reinterpret_cast<bf16x8*>(&ehl[0][k][pos]) =
        *reinterpret_cast<const bf16x8*>(eh_g + k * DIM + cl * 8);
    *reinterpret_cast<bf16x8*>(&ehl[1][k][pos]) =
        *reinterpret_cast<const bf16x8*>(el_g + k * DIM + cl * 8);
  }

  // ---- per-wave x staging: lane stages row lo, d-chunk hi*16..+15
  float xsq = 0.f;
#pragma unroll
  for (int j = 0; j < 16; ++j) {
    const int d = hi * 16 + j;
    const float f = x_g[(size_t)d * NTOT + n0w + lo];
    xsq = fmaf(f, f, xsq);
    const unsigned short h = f2bf(f);
    const unsigned short l2 = f2bf(f - bf2f(h));
    const int pos = ((((d >> 3) ^ (lo & 7)) << 3) | (d & 7));
    xls[w][0][lo][pos] = h;
    xls[w][1][lo][pos] = l2;
  }
  xsq += __shfl_xor(xsq, 16, 64);
  xsq += __shfl_xor(xsq, 32, 64);               // |x[row lo]|^2 in all 4 d-lanes

  // ---- embsq -> regs (kc fully unrolled => static indexing, no scratch)
  float eqr[32];
#pragma unroll
  for (int i = 0; i < 32; ++i) eqr[i] = embsq[i * 16 + lo];

  __syncthreads();   // ehl visible block-wide; also orders xls writes

  // ---- A-frags: af[ds][hl]; lane holds X[row=lo][k=ds*32+hi*8 .. +7]
  bf16x8 af[2][2];
#pragma unroll
  for (int ds = 0; ds < 2; ++ds) {
    const int ca = (ds * 4 + hi) ^ (lo & 7);
#pragma unroll
    for (int hl = 0; hl < 2; ++hl)
      af[ds][hl] = *reinterpret_cast<const bf16x8*>(&xls[w][hl][lo][ca << 3]);
  }

  // ---- |x|^2 for this lane's 4 C rows (C: row = hi*4+j, col = lo)
  float xsq_r[4];
#pragma unroll
  for (int j = 0; j < 4; ++j) xsq_r[j] = __shfl(xsq, hi * 4 + j, 64);

  unsigned long long mn[4] = {~0ull, ~0ull, ~0ull, ~0ull};

  // ---- main loop: 32 k-groups of 16 codes; NO global loads inside
#pragma unroll
  for (int kc = 0; kc < 8; ++kc) {
#pragma unroll
    for (int kg = 0; kg < 4; ++kg) {
      const int kcode = kc * 64 + kg * 16 + lo;
      const int cb0 = hi ^ (kcode & 7);
      const int cb1 = (4 + hi) ^ (kcode & 7);
      const bf16x8 beh0 = *reinterpret_cast<const bf16x8*>(&ehl[0][kcode][cb0 << 3]);
      const bf16x8 bel0 = *reinterpret_cast<const bf16x8*>(&ehl[1][kcode][cb0 << 3]);
      const bf16x8 beh1 = *reinterpret_cast<const bf16x8*>(&ehl[0][kcode][cb1 << 3]);
      const bf16x8 bel1 = *reinterpret_cast<const bf16x8*>(&ehl[1][kcode][cb1 << 3]);
      f32x4 a = (f32x4){0.f, 0.f, 0.f, 0.f};
      a = __builtin_amdgcn_mfma_f32_16x16x32_bf16(af[0][0], beh0, a, 0, 0, 0);
      a = __builtin_amdgcn_mfma_f32_16x16x32_bf16(af[0][0], bel0, a, 0, 0, 0);
      a = __builtin_amdgcn_mfma_f32_16x16x32_bf16(af[0][1], beh0, a, 0, 0, 0);
      a = __builtin_amdgcn_mfma_f32_16x16x32_bf16(af[1][0], beh1, a, 0, 0, 0);
      a = __builtin_amdgcn_mfma_f32_16x16x32_bf16(af[1][0], bel1, a, 0, 0, 0);
      a = __builtin_amdgcn_mfma_f32_16x16x32_bf16(af[1][1], beh1, a, 0, 0, 0);
      const float eq = eqr[kc * 4 + kg];
#pragma unroll
      for (int j = 0; j < 4; ++j) {
        const float dist = a[j] + xsq_r[j] + eq;
        dist_out[(size_t)(n0w + hi * 4 + j) * KCB + kcode] = dist;
        const unsigned long long pk =
            ((unsigned long long)__float_as_uint(dist) << 32) | (unsigned)kcode;
        mn[j] = pk < mn[j] ? pk : mn[j];
      }
    }
  }

  // ---- in-wave argmin: reduce over the 16 lo-lanes (rows are hi-local)
#pragma unroll
  for (int j = 0; j < 4; ++j) {
#pragma unroll
    for (int m = 1; m < 16; m <<= 1) {
      const unsigned long long o = __shfl_xor(mn[j], m, 64);
      mn[j] = o < mn[j] ? o : mn[j];
    }
  }

  // ---- idx + cnt (lanes lo==0 own 4 rows each)
  if (lo == 0) {
#pragma unroll
    for (int j = 0; j < 4; ++j) {
      const int km = (int)(mn[j] & 0xFFFFFFFFull);
      idx_out[n0w + hi * 4 + j] = km;
      atomicAdd(&cnt_g[km], 1u);
    }
  }

  // ---- enc one-hot + dw scatter for the wave's 16 rows
#pragma unroll
  for (int rr = 0; rr < 16; ++rr) {
    const int km = (int)(__shfl(mn[rr & 3], (rr >> 2) << 4, 64) & 0xFFFFFFFFull);
    const int base = lane * 8;
    float4 z0, z1;
    z0.x = (km == base)     ? 1.f : 0.f;
    z0.y = (km == base + 1) ? 1.f : 0.f;
    z0.z = (km == base + 2) ? 1.f : 0.f;
    z0.w = (km == base + 3) ? 1.f : 0.f;
    z1.x = (km == base + 4) ? 1.f : 0.f;
    z1.y = (km == base + 5) ? 1.f : 0.f;
    z1.z = (km == base + 6) ? 1.f : 0.f;
    z1.w = (km == base + 7) ? 1.f : 0.f;
    float* ep = enc_out + (size_t)(n0w + rr) * KCB + base;
    *reinterpret_cast<float4*>(ep) = z0;
    *reinterpret_cast<float4*>(ep + 4) = z1;

    const int c = ((lane >> 3) ^ (rr & 7));
    const float xv = bf2f(xls[w][0][rr][(c << 3) | (lane & 7)]) +
                     bf2f(xls[w][1][rr][(c << 3) | (lane & 7)]);
    unsafeAtomicAdd(dw_g + ((size_t)km << 6) + lane, xv);
  }
}

// ---------------------------------------------------------------------------
// K3: cluster EMA + laplace + new_emb + perplexity (1 block, 512 threads)
// ---------------------------------------------------------------------------
__global__ __launch_bounds__(512, 1) void k_final(
    const float* __restrict__ ema_w, const float* __restrict__ ema_cs,
    const unsigned* __restrict__ cnt, const float* __restrict__ dw,
    float* __restrict__ nemb, float* __restrict__ out)
{
  __shared__ float red[8];
  __shared__ float bc;
  const int t = threadIdx.x;
  const int lane = t & 63, w = t >> 6;

  const float c = (float)cnt[t];
  const float craw = ema_cs[t] * 0.99f + 0.01f * c;

  float s = wave_sum(craw);
  if (lane == 0) red[w] = s;
  __syncthreads();
  if (t == 0) {
    float a = 0.f;
#pragma unroll
    for (int i = 0; i < 8; ++i) a += red[i];
    bc = a;
  }
  __syncthreads();
  const float n = bc;
  const float clus = (craw + 1e-5f) / (n + 512.f * 1e-5f) * n;

  const float4* wr = reinterpret_cast<const float4*>(ema_w + t * 64);
  const float4* dr = reinterpret_cast<const float4*>(dw + t * 64);
  float4* nr = reinterpret_cast<float4*>(nemb + t * 64);
#pragma unroll
  for (int q = 0; q < 16; ++q) {
    const float4 wv = wr[q], dv = dr[q];
    float4 o;
    o.x = (wv.x * 0.99f + 0.01f * dv.x) / clus;
    o.y = (wv.y * 0.99f + 0.01f * dv.y) / clus;
    o.z = (wv.z * 0.99f + 0.01f * dv.z) / clus;
    o.w = (wv.w * 0.99f + 0.01f * dv.w) / clus;
    nr[q] = o;
  }

  const float p = c * (1.f / 131072.f);
  const float term = p * logf(p + 1e-10f);
  float s2 = wave_sum(term);
  if (lane == 0) red[w] = s2;
  __syncthreads();
  if (t == 0) {
    float a = 0.f;
#pragma unroll
    for (int i = 0; i < 8; ++i) a += red[i];
    out[8388609] = expf(-a);   // perplexity slot
  }
}

// ---------------------------------------------------------------------------
// K4: quantized gather + transposed write + commitment loss
// ---------------------------------------------------------------------------
__global__ __launch_bounds__(256, 4) void k_quant(
    const float* __restrict__ x_g, const int* __restrict__ idx_g,
    const float* __restrict__ nemb, float* __restrict__ out)
{
  float lsum = 0.f;
  const int stride = gridDim.x * 256;
  for (int i = blockIdx.x * 256 + threadIdx.x; i < (DIM * NTOT / 4); i += stride) {
    const int d = i >> 15;                 // / (NTOT/4)
    const int n4 = i & ((NTOT / 4) - 1);
    const float4 xv = *reinterpret_cast<const float4*>(x_g + ((size_t)d << 17) + 4 * n4);
    const int4 id = *reinterpret_cast<const int4*>(idx_g + 4 * n4);
    const float q0 = nemb[(id.x << 6) + d];
    const float q1 = nemb[(id.y << 6) + d];
    const float q2 = nemb[(id.z << 6) + d];
    const float q3 = nemb[(id.w << 6) + d];
    const float e0 = q0 - xv.x, e1 = q1 - xv.y, e2 = q2 - xv.z, e3 = q3 - xv.w;
    float* op = out + 1 + ((size_t)d << 17) + 4 * n4;   // quantized_st region
    op[0] = xv.x + e0;
    op[1] = xv.y + e1;
    op[2] = xv.z + e2;
    op[3] = xv.w + e3;
    lsum += e0 * e0 + e1 * e1 + e2 * e2 + e3 * e3;
  }
  lsum = wave_sum(lsum);
  __shared__ float wsum[4];
  const int lane = threadIdx.x & 63, w = threadIdx.x >> 6;
  if (lane == 0) wsum[w] = lsum;
  __syncthreads();
  if (threadIdx.x == 0)
    unsafeAtomicAdd(out, (wsum[0] + wsum[1] + wsum[2] + wsum[3]) * (0.25f / 8388608.f));
}

// ---------------------------------------------------------------------------
extern "C" void kernel_launch(void* const* d_in, const int* in_sizes, int n_in,
                              void* d_out, int out_size, void* d_ws, size_t ws_size,
                              hipStream_t stream) {
  const float* x      = (const float*)d_in[0];   // [64][16][8192]
  const float* emb    = (const float*)d_in[1];   // [512][64]
  const float* ema_w  = (const float*)d_in[2];   // [512][64]
  const float* ema_cs = (const float*)d_in[3];   // [512]
  float* out = (float*)d_out;

  // d_out: loss@0 | q@1 (8388608) | perp@8388609 | enc@8388610 | dist@75497474
  float* enc_out  = out + 8388610;
  float* dist_out = out + 75497474;

  // ws: dw@0 (131072) | cnt@131072 (2048) | nemb@133120 (131072) |
  //     idx@264192 (524288) | embsq@788480 (2048) | eh@790528 (65536) |
  //     el@856064 (65536)
  char* ws = (char*)d_ws;
  float*          dw    = (float*)ws;
  unsigned*       cnt   = (unsigned*)(ws + 131072);
  float*          nemb  = (float*)(ws + 133120);
  int*            idx   = (int*)(ws + 264192);
  float*          embsq = (float*)(ws + 788480);
  unsigned short* eh    = (unsigned short*)(ws + 790528);
  unsigned short* el    = (unsigned short*)(ws + 856064);

  hipMemsetAsync(d_ws, 0, 133120, stream);          // zero dw + counts
  hipMemsetAsync(d_out, 0, sizeof(float), stream);  // zero loss accumulator

  k_prep<<<1, 512, 0, stream>>>(emb, eh, el, embsq);
  k_dist<<<1024, 512, 0, stream>>>(x, eh, el, embsq, dist_out, enc_out, idx, cnt, dw);
  k_final<<<1, 512, 0, stream>>>(ema_w, ema_cs, cnt, dw, nemb, out);
  k_quant<<<2048, 256, 0, stream>>>(x, idx, nemb, out);
}